// Round 1
// baseline (586.293 us; speedup 1.0000x reference)
//
#include <hip/hip_runtime.h>
#include <hip/hip_bf16.h>

// 3-layer GCN encoder on MI355X.
// Pipeline per call:
//   1. cnt = histogram(dst)                  (int atomics)
//   2. off = exclusive_scan(cnt); cur = off; dinv = rsqrt(cnt+1)
//   3. col = CSR column indices (scatter by dst)
//   4. per layer L: g = (h @ W_L) * dinv     (GEMM + scale epilogue)
//                   h = act(dinv * (sum_{s in N(d)} g[s] + g[d]) + b_L)
// norm[e] = dinv[src]*dinv[dst] is factored into the two dinv scalings,
// turning the scatter-add into a gather-only CSR reduction (no f32 atomics).

#define IN_DIM 64
#define HID_DIM 64
#define LAT_DIM 32

// ---------------- CSR construction ----------------

__global__ void hist_kernel(const int* __restrict__ dst, int* __restrict__ cnt, int E) {
    int e = blockIdx.x * blockDim.x + threadIdx.x;
    if (e < E) atomicAdd(&cnt[dst[e]], 1);
}

// Single-block chunked Hillis-Steele scan. N=50000 -> 49 chunks of 1024.
__global__ void scan_kernel(const int* __restrict__ cnt, int* __restrict__ off,
                            int* __restrict__ cur, float* __restrict__ dinv, int N) {
    __shared__ int sdata[1024];
    __shared__ int s_total;
    int tid = threadIdx.x;
    if (tid == 0) { s_total = 0; off[0] = 0; }
    __syncthreads();
    for (int base = 0; base < N; base += 1024) {
        int i = base + tid;
        int v = (i < N) ? cnt[i] : 0;
        sdata[tid] = v;
        __syncthreads();
        #pragma unroll
        for (int s = 1; s < 1024; s <<= 1) {
            int t = (tid >= s) ? sdata[tid - s] : 0;
            __syncthreads();
            sdata[tid] += t;
            __syncthreads();
        }
        int incl = sdata[tid];
        int total = s_total;      // everyone reads old running total
        __syncthreads();
        if (tid == 1023) s_total = total + incl;
        if (i < N) {
            off[i + 1] = total + incl;
            cur[i]     = total + incl - v;       // exclusive
            dinv[i]    = rsqrtf((float)(v + 1)); // +1 for self loop; always > 0
        }
        __syncthreads();
    }
}

__global__ void scatter_kernel(const int* __restrict__ src, const int* __restrict__ dst,
                               int* __restrict__ cur, int* __restrict__ col, int E) {
    int e = blockIdx.x * blockDim.x + threadIdx.x;
    if (e < E) {
        int d = dst[e];
        int p = atomicAdd(&cur[d], 1);
        col[p] = src[e];
    }
}

// ---------------- GEMM (N x 64) @ (64 x OUT), scaled by dinv[row] ----------------
// One thread per output element. Wave lanes share a row -> x loads are
// broadcast (L1 hit); W staged in LDS (lane-consecutive reads, conflict-free).

template<int OUT>
__global__ void gemm_scale_kernel(const float* __restrict__ X, const float* __restrict__ W,
                                  const float* __restrict__ dinv, float* __restrict__ G, int N) {
    __shared__ float Ws[IN_DIM * OUT];
    int tid = threadIdx.x;
    for (int i = tid; i < IN_DIM * OUT; i += blockDim.x) Ws[i] = W[i];
    __syncthreads();
    constexpr int ROWS = 256 / OUT;          // 4 (OUT=64) or 8 (OUT=32)
    int c = tid % OUT;
    int r = tid / OUT;
    int row = blockIdx.x * ROWS + r;
    if (row >= N) return;
    const float* xr = X + (size_t)row * IN_DIM;
    float acc = 0.f;
    #pragma unroll
    for (int k = 0; k < IN_DIM; ++k) acc += xr[k] * Ws[k * OUT + c];
    G[(size_t)row * OUT + c] = acc * dinv[row];
}

// ---------------- CSR aggregation: one wave per node ----------------
// acc starts at g[node] (self loop); neighbors gathered as coalesced 256B rows.

template<int D, bool TANH>
__global__ void agg_kernel(const float* __restrict__ G, const int* __restrict__ off,
                           const int* __restrict__ col, const float* __restrict__ dinv,
                           const float* __restrict__ b, float* __restrict__ H, int N) {
    int tid  = threadIdx.x;
    int lane = tid & 63;
    int w    = tid >> 6;
    int node = blockIdx.x * 4 + w;
    if (node >= N) return;
    if (lane >= D) return;
    float acc = G[(size_t)node * D + lane];   // self-loop contribution
    int p0 = off[node], p1 = off[node + 1];
    for (int p = p0; p < p1; ++p) {
        int s = col[p];
        acc += G[(size_t)s * D + lane];
    }
    float v = dinv[node] * acc + b[lane];
    H[(size_t)node * D + lane] = TANH ? tanhf(v) : v;
}

// ---------------- launch ----------------

static inline size_t align256(size_t x) { return (x + 255) & ~(size_t)255; }

extern "C" void kernel_launch(void* const* d_in, const int* in_sizes, int n_in,
                              void* d_out, int out_size, void* d_ws, size_t ws_size,
                              hipStream_t stream) {
    const float* x   = (const float*)d_in[0];
    const int*   ei  = (const int*)d_in[1];
    const float* W1  = (const float*)d_in[2];
    const float* b1  = (const float*)d_in[3];
    const float* W2  = (const float*)d_in[4];
    const float* b2  = (const float*)d_in[5];
    const float* W3  = (const float*)d_in[6];
    const float* b3  = (const float*)d_in[7];
    float* out = (float*)d_out;

    const int N = in_sizes[0] / IN_DIM;   // 50000
    const int E = in_sizes[1] / 2;        // 800000
    const int* src = ei;
    const int* dst = ei + E;

    // workspace layout
    char* ws = (char*)d_ws;
    size_t o = 0;
    int*   cnt  = (int*)(ws + o);  o = align256(o + (size_t)N * 4);
    int*   off  = (int*)(ws + o);  o = align256(o + (size_t)(N + 1) * 4);
    int*   cur  = (int*)(ws + o);  o = align256(o + (size_t)N * 4);
    float* dinv = (float*)(ws + o); o = align256(o + (size_t)N * 4);
    int*   col  = (int*)(ws + o);  o = align256(o + (size_t)E * 4);
    float* bufG = (float*)(ws + o); o = align256(o + (size_t)N * HID_DIM * 4);
    float* bufH = (float*)(ws + o); o = align256(o + (size_t)N * HID_DIM * 4);
    (void)ws_size;

    // 1. degree histogram
    hipMemsetAsync(cnt, 0, (size_t)N * 4, stream);
    hist_kernel<<<(E + 255) / 256, 256, 0, stream>>>(dst, cnt, E);

    // 2. scan -> off/cur/dinv
    scan_kernel<<<1, 1024, 0, stream>>>(cnt, off, cur, dinv, N);

    // 3. CSR columns
    scatter_kernel<<<(E + 255) / 256, 256, 0, stream>>>(src, dst, cur, col, E);

    const int gemm64_grid = (N + 3) / 4;
    const int gemm32_grid = (N + 7) / 8;
    const int agg_grid    = (N + 3) / 4;

    // layer 1: g1 = (x @ W1) * dinv ; h1 = tanh(dinv * agg(g1) + b1)
    gemm_scale_kernel<HID_DIM><<<gemm64_grid, 256, 0, stream>>>(x, W1, dinv, bufG, N);
    agg_kernel<HID_DIM, true><<<agg_grid, 256, 0, stream>>>(bufG, off, col, dinv, b1, bufH, N);

    // layer 2
    gemm_scale_kernel<HID_DIM><<<gemm64_grid, 256, 0, stream>>>(bufH, W2, dinv, bufG, N);
    agg_kernel<HID_DIM, true><<<agg_grid, 256, 0, stream>>>(bufG, off, col, dinv, b2, bufH, N);

    // layer 3 (no tanh, D=32) -> d_out
    gemm_scale_kernel<LAT_DIM><<<gemm32_grid, 256, 0, stream>>>(bufH, W3, dinv, bufG, N);
    agg_kernel<LAT_DIM, false><<<agg_grid, 256, 0, stream>>>(bufG, off, col, dinv, b3, out, N);
}

// Round 2
// 366.907 us; speedup vs baseline: 1.5979x; 1.5979x over previous
//
#include <hip/hip_runtime.h>
#include <hip/hip_bf16.h>

// 3-layer GCN encoder on MI355X.
//   1. cnt = histogram(dst)                          (int atomics)
//   2. off = exclusive_scan(cnt)  [3-kernel scan]; dinv = rsqrt(cnt+1)
//   3. col = CSR column indices (scatter by dst)
//   4. per layer: g = (h @ W) * dinv ; h = act(dinv * (sum_{s in N(d)} g[s] + g[d]) + b)
// norm factored into two dinv scalings -> gather-only CSR reduction, no f32 atomics.
// R2: replaced 95us single-block scan with 3-kernel device scan; 4x MLP unroll in agg;
//     2 nodes/wave for the D=32 layer.

#define IN_DIM 64
#define HID_DIM 64
#define LAT_DIM 32

// ---------------- CSR construction ----------------

__global__ void hist_kernel(const int* __restrict__ dst, int* __restrict__ cnt, int E) {
    int e = blockIdx.x * blockDim.x + threadIdx.x;
    if (e < E) atomicAdd(&cnt[dst[e]], 1);
}

// ---- scan kernel A: per-block (1024 elems, 256 thr x int4) inclusive scan ----
__global__ __launch_bounds__(256) void scan_a(const int* __restrict__ cnt,
                                              int* __restrict__ incl,
                                              int* __restrict__ bsum, int N) {
    __shared__ int wsum[4];
    int tid = threadIdx.x;
    int i0 = blockIdx.x * 1024 + tid * 4;
    int4 v = make_int4(0, 0, 0, 0);
    if (i0 + 3 < N) v = *(const int4*)(cnt + i0);
    else {
        if (i0 + 0 < N) v.x = cnt[i0 + 0];
        if (i0 + 1 < N) v.y = cnt[i0 + 1];
        if (i0 + 2 < N) v.z = cnt[i0 + 2];
        if (i0 + 3 < N) v.w = cnt[i0 + 3];
    }
    int s1 = v.x + v.y, s2 = s1 + v.z, s3 = s2 + v.w;  // thread-local inclusive
    int lane = tid & 63, wid = tid >> 6;
    int sc = s3;
    #pragma unroll
    for (int d = 1; d < 64; d <<= 1) {
        int t = __shfl_up(sc, d, 64);
        if (lane >= d) sc += t;
    }
    if (lane == 63) wsum[wid] = sc;
    __syncthreads();
    int woff = 0;
    #pragma unroll
    for (int w = 0; w < 4; ++w) if (w < wid) woff += wsum[w];
    int excl = woff + sc - s3;  // exclusive prefix of this thread's 4 elems
    int o0 = excl + v.x, o1 = excl + s1, o2 = excl + s2, o3 = excl + s3;
    if (i0 + 3 < N) *(int4*)(incl + i0) = make_int4(o0, o1, o2, o3);
    else {
        if (i0 + 0 < N) incl[i0 + 0] = o0;
        if (i0 + 1 < N) incl[i0 + 1] = o1;
        if (i0 + 2 < N) incl[i0 + 2] = o2;
        if (i0 + 3 < N) incl[i0 + 3] = o3;
    }
    if (tid == 255) bsum[blockIdx.x] = woff + sc;  // block total
}

// ---- scan kernel B: exclusive scan of <=64 block sums in one wave ----
__global__ void scan_b(int* __restrict__ bsum, int NB) {
    int lane = threadIdx.x;
    int v = (lane < NB) ? bsum[lane] : 0;
    int sc = v;
    #pragma unroll
    for (int d = 1; d < 64; d <<= 1) {
        int t = __shfl_up(sc, d, 64);
        if (lane >= d) sc += t;
    }
    if (lane < NB) bsum[lane] = sc - v;  // exclusive
}

// ---- scan kernel C: fixup + off/cur/dinv ----
__global__ __launch_bounds__(256) void scan_c(const int* __restrict__ cnt,
                                              const int* __restrict__ incl,
                                              const int* __restrict__ bsum,
                                              int* __restrict__ off, int* __restrict__ cur,
                                              float* __restrict__ dinv, int N) {
    int i = blockIdx.x * blockDim.x + threadIdx.x;
    if (i == 0) off[0] = 0;
    if (i < N) {
        int t = incl[i] + bsum[i >> 10];
        int c = cnt[i];
        off[i + 1] = t;
        cur[i]     = t - c;
        dinv[i]    = rsqrtf((float)(c + 1));
    }
}

__global__ void scatter_kernel(const int* __restrict__ src, const int* __restrict__ dst,
                               int* __restrict__ cur, int* __restrict__ col, int E) {
    int e = blockIdx.x * blockDim.x + threadIdx.x;
    if (e < E) {
        int d = dst[e];
        int p = atomicAdd(&cur[d], 1);
        col[p] = src[e];
    }
}

// ---------------- GEMM (N x 64) @ (64 x OUT), scaled by dinv[row] ----------------

template<int OUT>
__global__ __launch_bounds__(256) void gemm_scale_kernel(const float* __restrict__ X,
                                  const float* __restrict__ W,
                                  const float* __restrict__ dinv, float* __restrict__ G, int N) {
    __shared__ float Ws[IN_DIM * OUT];
    int tid = threadIdx.x;
    for (int i = tid; i < IN_DIM * OUT; i += blockDim.x) Ws[i] = W[i];
    __syncthreads();
    constexpr int ROWS = 256 / OUT;  // 4 (OUT=64) or 8 (OUT=32)
    int c = tid % OUT;
    int r = tid / OUT;
    int row = blockIdx.x * ROWS + r;
    if (row >= N) return;
    const float* xr = X + (size_t)row * IN_DIM;
    float acc = 0.f;
    #pragma unroll
    for (int k = 0; k < IN_DIM; ++k) acc += xr[k] * Ws[k * OUT + c];
    G[(size_t)row * OUT + c] = acc * dinv[row];
}

// ---------------- CSR aggregation ----------------
// 64/D nodes per wave (all lanes active), 4-way unrolled gather for MLP.

template<int D, bool TANH>
__global__ __launch_bounds__(256) void agg_kernel(const float* __restrict__ G,
                           const int* __restrict__ off,
                           const int* __restrict__ col, const float* __restrict__ dinv,
                           const float* __restrict__ b, float* __restrict__ H, int N) {
    constexpr int NPW = 64 / D;                 // nodes per wave
    int tid  = threadIdx.x;
    int lane = tid & 63;
    int w    = tid >> 6;
    int sub  = lane / D;
    int ld   = lane % D;
    int node = (blockIdx.x * 4 + w) * NPW + sub;
    if (node >= N) return;
    float a0 = G[(size_t)node * D + ld];        // self-loop contribution
    float a1 = 0.f, a2 = 0.f, a3 = 0.f;
    int p  = off[node];
    int p1 = off[node + 1];
    for (; p + 3 < p1; p += 4) {
        int s0 = col[p], s1 = col[p + 1], s2 = col[p + 2], s3 = col[p + 3];
        a0 += G[(size_t)s0 * D + ld];
        a1 += G[(size_t)s1 * D + ld];
        a2 += G[(size_t)s2 * D + ld];
        a3 += G[(size_t)s3 * D + ld];
    }
    for (; p < p1; ++p) a0 += G[(size_t)col[p] * D + ld];
    float v = dinv[node] * ((a0 + a1) + (a2 + a3)) + b[ld];
    H[(size_t)node * D + ld] = TANH ? tanhf(v) : v;
}

// ---------------- launch ----------------

static inline size_t align256(size_t x) { return (x + 255) & ~(size_t)255; }

extern "C" void kernel_launch(void* const* d_in, const int* in_sizes, int n_in,
                              void* d_out, int out_size, void* d_ws, size_t ws_size,
                              hipStream_t stream) {
    const float* x   = (const float*)d_in[0];
    const int*   ei  = (const int*)d_in[1];
    const float* W1  = (const float*)d_in[2];
    const float* b1  = (const float*)d_in[3];
    const float* W2  = (const float*)d_in[4];
    const float* b2  = (const float*)d_in[5];
    const float* W3  = (const float*)d_in[6];
    const float* b3  = (const float*)d_in[7];
    float* out = (float*)d_out;

    const int N = in_sizes[0] / IN_DIM;   // 50000
    const int E = in_sizes[1] / 2;        // 800000
    const int* src = ei;
    const int* dst = ei + E;
    const int NB = (N + 1023) / 1024;     // 49 scan blocks

    // workspace layout
    char* ws = (char*)d_ws;
    size_t o = 0;
    int*   cnt  = (int*)(ws + o);   o = align256(o + (size_t)N * 4);
    int*   off  = (int*)(ws + o);   o = align256(o + (size_t)(N + 1) * 4);
    int*   cur  = (int*)(ws + o);   o = align256(o + (size_t)N * 4);
    float* dinv = (float*)(ws + o); o = align256(o + (size_t)N * 4);
    int*   incl = (int*)(ws + o);   o = align256(o + (size_t)N * 4);
    int*   bsum = (int*)(ws + o);   o = align256(o + (size_t)NB * 4);
    int*   col  = (int*)(ws + o);   o = align256(o + (size_t)E * 4);
    float* bufG = (float*)(ws + o); o = align256(o + (size_t)N * HID_DIM * 4);
    float* bufH = (float*)(ws + o); o = align256(o + (size_t)N * HID_DIM * 4);
    (void)ws_size;

    // 1. degree histogram
    hipMemsetAsync(cnt, 0, (size_t)N * 4, stream);
    hist_kernel<<<(E + 255) / 256, 256, 0, stream>>>(dst, cnt, E);

    // 2. device-wide scan -> off/cur/dinv
    scan_a<<<NB, 256, 0, stream>>>(cnt, incl, bsum, N);
    scan_b<<<1, 64, 0, stream>>>(bsum, NB);
    scan_c<<<(N + 255) / 256, 256, 0, stream>>>(cnt, incl, bsum, off, cur, dinv, N);

    // 3. CSR columns
    scatter_kernel<<<(E + 255) / 256, 256, 0, stream>>>(src, dst, cur, col, E);

    const int gemm64_grid = (N + 3) / 4;
    const int gemm32_grid = (N + 7) / 8;
    const int agg64_grid  = (N + 3) / 4;        // 1 node/wave * 4 waves
    const int agg32_grid  = (N + 7) / 8;        // 2 nodes/wave * 4 waves

    // layer 1
    gemm_scale_kernel<HID_DIM><<<gemm64_grid, 256, 0, stream>>>(x, W1, dinv, bufG, N);
    agg_kernel<HID_DIM, true><<<agg64_grid, 256, 0, stream>>>(bufG, off, col, dinv, b1, bufH, N);

    // layer 2
    gemm_scale_kernel<HID_DIM><<<gemm64_grid, 256, 0, stream>>>(bufH, W2, dinv, bufG, N);
    agg_kernel<HID_DIM, true><<<agg64_grid, 256, 0, stream>>>(bufG, off, col, dinv, b2, bufH, N);

    // layer 3 (no tanh, D=32) -> d_out
    gemm_scale_kernel<LAT_DIM><<<gemm32_grid, 256, 0, stream>>>(bufH, W3, dinv, bufG, N);
    agg_kernel<LAT_DIM, false><<<agg32_grid, 256, 0, stream>>>(bufG, off, col, dinv, b3, out, N);
}

// Round 3
// 313.200 us; speedup vs baseline: 1.8719x; 1.1715x over previous
//
#include <hip/hip_runtime.h>
#include <hip/hip_bf16.h>

// 3-layer GCN encoder on MI355X.
//   1. cnt = histogram(dst)                          (int atomics)
//   2. off = exclusive_scan(cnt)  [3-kernel scan]; dinv = rsqrt(cnt+1)
//   3. col = CSR column indices (scatter by dst)
//   4. per layer: g = (h @ W) * dinv ; h = act(dinv * (sum_{s in N(d)} g[s] + g[d]) + b)
// norm factored into two dinv scalings -> gather-only CSR reduction, no f32 atomics.
// R3: register-tiled LDS GEMM (4x4 per thread, transposed X tile) replaces
//     latency-bound scalar-load GEMM; agg unroll 8; NT loads on edge streams.

#define IN_DIM 64
#define HID_DIM 64
#define LAT_DIM 32

// ---------------- CSR construction ----------------

__global__ void hist_kernel(const int* __restrict__ dst, int* __restrict__ cnt, int E) {
    int e = blockIdx.x * blockDim.x + threadIdx.x;
    if (e < E) atomicAdd(&cnt[__builtin_nontemporal_load(dst + e)], 1);
}

// ---- scan kernel A: per-block (1024 elems, 256 thr x int4) inclusive scan ----
__global__ __launch_bounds__(256) void scan_a(const int* __restrict__ cnt,
                                              int* __restrict__ incl,
                                              int* __restrict__ bsum, int N) {
    __shared__ int wsum[4];
    int tid = threadIdx.x;
    int i0 = blockIdx.x * 1024 + tid * 4;
    int4 v = make_int4(0, 0, 0, 0);
    if (i0 + 3 < N) v = *(const int4*)(cnt + i0);
    else {
        if (i0 + 0 < N) v.x = cnt[i0 + 0];
        if (i0 + 1 < N) v.y = cnt[i0 + 1];
        if (i0 + 2 < N) v.z = cnt[i0 + 2];
        if (i0 + 3 < N) v.w = cnt[i0 + 3];
    }
    int s1 = v.x + v.y, s2 = s1 + v.z, s3 = s2 + v.w;  // thread-local inclusive
    int lane = tid & 63, wid = tid >> 6;
    int sc = s3;
    #pragma unroll
    for (int d = 1; d < 64; d <<= 1) {
        int t = __shfl_up(sc, d, 64);
        if (lane >= d) sc += t;
    }
    if (lane == 63) wsum[wid] = sc;
    __syncthreads();
    int woff = 0;
    #pragma unroll
    for (int w = 0; w < 4; ++w) if (w < wid) woff += wsum[w];
    int excl = woff + sc - s3;  // exclusive prefix of this thread's 4 elems
    int o0 = excl + v.x, o1 = excl + s1, o2 = excl + s2, o3 = excl + s3;
    if (i0 + 3 < N) *(int4*)(incl + i0) = make_int4(o0, o1, o2, o3);
    else {
        if (i0 + 0 < N) incl[i0 + 0] = o0;
        if (i0 + 1 < N) incl[i0 + 1] = o1;
        if (i0 + 2 < N) incl[i0 + 2] = o2;
        if (i0 + 3 < N) incl[i0 + 3] = o3;
    }
    if (tid == 255) bsum[blockIdx.x] = woff + sc;  // block total
}

// ---- scan kernel B: exclusive scan of <=64 block sums in one wave ----
__global__ void scan_b(int* __restrict__ bsum, int NB) {
    int lane = threadIdx.x;
    int v = (lane < NB) ? bsum[lane] : 0;
    int sc = v;
    #pragma unroll
    for (int d = 1; d < 64; d <<= 1) {
        int t = __shfl_up(sc, d, 64);
        if (lane >= d) sc += t;
    }
    if (lane < NB) bsum[lane] = sc - v;  // exclusive
}

// ---- scan kernel C: fixup + off/cur/dinv ----
__global__ __launch_bounds__(256) void scan_c(const int* __restrict__ cnt,
                                              const int* __restrict__ incl,
                                              const int* __restrict__ bsum,
                                              int* __restrict__ off, int* __restrict__ cur,
                                              float* __restrict__ dinv, int N) {
    int i = blockIdx.x * blockDim.x + threadIdx.x;
    if (i == 0) off[0] = 0;
    if (i < N) {
        int t = incl[i] + bsum[i >> 10];
        int c = cnt[i];
        off[i + 1] = t;
        cur[i]     = t - c;
        dinv[i]    = rsqrtf((float)(c + 1));
    }
}

__global__ void scatter_kernel(const int* __restrict__ src, const int* __restrict__ dst,
                               int* __restrict__ cur, int* __restrict__ col, int E) {
    int e = blockIdx.x * blockDim.x + threadIdx.x;
    if (e < E) {
        int d = __builtin_nontemporal_load(dst + e);
        int s = __builtin_nontemporal_load(src + e);
        int p = atomicAdd(&cur[d], 1);
        col[p] = s;
    }
}

// ---------------- GEMM (N x 64) @ (64 x OUT), scaled by dinv[row] ----------------
// Register-tiled: 256 threads, RT rows/block, 4x4 outputs/thread.
// W staged [k][c]; X staged transposed [k][row] (pad +4 -> conflict-free b128 reads).

template<int OUT, int RT>
__global__ __launch_bounds__(256) void gemm_tile_kernel(const float* __restrict__ X,
                                                        const float* __restrict__ W,
                                                        const float* __restrict__ dinv,
                                                        float* __restrict__ G, int N) {
    constexpr int CG = OUT / 4;    // col groups (16 or 8)
    static_assert(256 / CG * 4 == RT, "RT must match 4*(256/CG)");
    __shared__ float Ws[64 * OUT];
    __shared__ float XsT[64][RT + 4];
    int tid = threadIdx.x;
    int row0 = blockIdx.x * RT;

    for (int f = 4 * tid; f < 64 * OUT; f += 1024)
        *(float4*)&Ws[f] = *(const float4*)&W[f];

    for (int f = 4 * tid; f < RT * 64; f += 1024) {
        int r  = f >> 6;
        int k0 = f & 63;
        int gr = row0 + r;
        float4 v = (gr < N) ? *(const float4*)&X[(size_t)gr * 64 + k0]
                            : make_float4(0.f, 0.f, 0.f, 0.f);
        XsT[k0 + 0][r] = v.x; XsT[k0 + 1][r] = v.y;
        XsT[k0 + 2][r] = v.z; XsT[k0 + 3][r] = v.w;
    }
    __syncthreads();

    int cr = tid % CG;
    int rr = tid / CG;
    float acc[4][4] = {};
    #pragma unroll 4
    for (int k = 0; k < 64; ++k) {
        float4 a = *(float4*)&XsT[k][4 * rr];
        float4 b = *(float4*)&Ws[k * OUT + 4 * cr];
        float av[4] = {a.x, a.y, a.z, a.w};
        float bv[4] = {b.x, b.y, b.z, b.w};
        #pragma unroll
        for (int j = 0; j < 4; ++j)
            #pragma unroll
            for (int i = 0; i < 4; ++i)
                acc[j][i] += av[j] * bv[i];
    }

    #pragma unroll
    for (int j = 0; j < 4; ++j) {
        int gr = row0 + 4 * rr + j;
        if (gr < N) {
            float s = dinv[gr];
            float4 o = make_float4(acc[j][0] * s, acc[j][1] * s,
                                   acc[j][2] * s, acc[j][3] * s);
            *(float4*)&G[(size_t)gr * OUT + 4 * cr] = o;
        }
    }
}

// ---------------- CSR aggregation ----------------
// 64/D nodes per wave (all lanes active), 8-way unrolled gather.

template<int D, bool TANH>
__global__ __launch_bounds__(256) void agg_kernel(const float* __restrict__ G,
                           const int* __restrict__ off,
                           const int* __restrict__ col, const float* __restrict__ dinv,
                           const float* __restrict__ b, float* __restrict__ H, int N) {
    constexpr int NPW = 64 / D;                 // nodes per wave
    int tid  = threadIdx.x;
    int lane = tid & 63;
    int w    = tid >> 6;
    int sub  = lane / D;
    int ld   = lane % D;
    int node = (blockIdx.x * 4 + w) * NPW + sub;
    if (node >= N) return;
    float a0 = G[(size_t)node * D + ld];        // self-loop contribution
    float a1 = 0.f, a2 = 0.f, a3 = 0.f, a4 = 0.f, a5 = 0.f, a6 = 0.f, a7 = 0.f;
    int p  = off[node];
    int p1 = off[node + 1];
    for (; p + 7 < p1; p += 8) {
        int s0 = col[p],     s1 = col[p + 1], s2 = col[p + 2], s3 = col[p + 3];
        int s4 = col[p + 4], s5 = col[p + 5], s6 = col[p + 6], s7 = col[p + 7];
        a0 += G[(size_t)s0 * D + ld];
        a1 += G[(size_t)s1 * D + ld];
        a2 += G[(size_t)s2 * D + ld];
        a3 += G[(size_t)s3 * D + ld];
        a4 += G[(size_t)s4 * D + ld];
        a5 += G[(size_t)s5 * D + ld];
        a6 += G[(size_t)s6 * D + ld];
        a7 += G[(size_t)s7 * D + ld];
    }
    for (; p < p1; ++p) a0 += G[(size_t)col[p] * D + ld];
    float acc = ((a0 + a1) + (a2 + a3)) + ((a4 + a5) + (a6 + a7));
    float v = dinv[node] * acc + b[ld];
    H[(size_t)node * D + ld] = TANH ? tanhf(v) : v;
}

// ---------------- launch ----------------

static inline size_t align256(size_t x) { return (x + 255) & ~(size_t)255; }

extern "C" void kernel_launch(void* const* d_in, const int* in_sizes, int n_in,
                              void* d_out, int out_size, void* d_ws, size_t ws_size,
                              hipStream_t stream) {
    const float* x   = (const float*)d_in[0];
    const int*   ei  = (const int*)d_in[1];
    const float* W1  = (const float*)d_in[2];
    const float* b1  = (const float*)d_in[3];
    const float* W2  = (const float*)d_in[4];
    const float* b2  = (const float*)d_in[5];
    const float* W3  = (const float*)d_in[6];
    const float* b3  = (const float*)d_in[7];
    float* out = (float*)d_out;

    const int N = in_sizes[0] / IN_DIM;   // 50000
    const int E = in_sizes[1] / 2;        // 800000
    const int* src = ei;
    const int* dst = ei + E;
    const int NB = (N + 1023) / 1024;     // 49 scan blocks

    // workspace layout
    char* ws = (char*)d_ws;
    size_t o = 0;
    int*   cnt  = (int*)(ws + o);   o = align256(o + (size_t)N * 4);
    int*   off  = (int*)(ws + o);   o = align256(o + (size_t)(N + 1) * 4);
    int*   cur  = (int*)(ws + o);   o = align256(o + (size_t)N * 4);
    float* dinv = (float*)(ws + o); o = align256(o + (size_t)N * 4);
    int*   incl = (int*)(ws + o);   o = align256(o + (size_t)N * 4);
    int*   bsum = (int*)(ws + o);   o = align256(o + (size_t)NB * 4);
    int*   col  = (int*)(ws + o);   o = align256(o + (size_t)E * 4);
    float* bufG = (float*)(ws + o); o = align256(o + (size_t)N * HID_DIM * 4);
    float* bufH = (float*)(ws + o); o = align256(o + (size_t)N * HID_DIM * 4);
    (void)ws_size;

    // 1. degree histogram
    hipMemsetAsync(cnt, 0, (size_t)N * 4, stream);
    hist_kernel<<<(E + 255) / 256, 256, 0, stream>>>(dst, cnt, E);

    // 2. device-wide scan -> off/cur/dinv
    scan_a<<<NB, 256, 0, stream>>>(cnt, incl, bsum, N);
    scan_b<<<1, 64, 0, stream>>>(bsum, NB);
    scan_c<<<(N + 255) / 256, 256, 0, stream>>>(cnt, incl, bsum, off, cur, dinv, N);

    // 3. CSR columns
    scatter_kernel<<<(E + 255) / 256, 256, 0, stream>>>(src, dst, cur, col, E);

    const int g64_grid = (N + 63) / 64;    // RT=64
    const int g32_grid = (N + 127) / 128;  // RT=128
    const int agg64_grid = (N + 3) / 4;    // 1 node/wave * 4 waves
    const int agg32_grid = (N + 7) / 8;    // 2 nodes/wave * 4 waves

    // layer 1
    gemm_tile_kernel<HID_DIM, 64><<<g64_grid, 256, 0, stream>>>(x, W1, dinv, bufG, N);
    agg_kernel<HID_DIM, true><<<agg64_grid, 256, 0, stream>>>(bufG, off, col, dinv, b1, bufH, N);

    // layer 2
    gemm_tile_kernel<HID_DIM, 64><<<g64_grid, 256, 0, stream>>>(bufH, W2, dinv, bufG, N);
    agg_kernel<HID_DIM, true><<<agg64_grid, 256, 0, stream>>>(bufG, off, col, dinv, b2, bufH, N);

    // layer 3 (no tanh, D=32) -> d_out
    gemm_tile_kernel<LAT_DIM, 128><<<g32_grid, 256, 0, stream>>>(bufH, W3, dinv, bufG, N);
    agg_kernel<LAT_DIM, false><<<agg32_grid, 256, 0, stream>>>(bufG, off, col, dinv, b3, out, N);
}

// Round 4
// 251.974 us; speedup vs baseline: 2.3268x; 1.2430x over previous
//
#include <hip/hip_runtime.h>
#include <hip/hip_bf16.h>

// 3-layer GCN encoder on MI355X.
//   CSR build (bucketed, no random global writes):
//     bin:    edges -> 196 buckets of 256 nodes (dst>>8), packed src|localdst<<16
//     bhist:  per-bucket LDS histogram -> cnt (coalesced)
//     scan:   off = exclusive_scan(cnt); dinv = rsqrt(cnt+1)
//     bscat:  per-bucket scatter, off staged in LDS, col writes L2-local
//   Per layer: g = (h @ W) * dinv ; h = act(dinv * (sum_{s in N(d)} g[s] + g[d]) + b)
// norm factored into two dinv scalings -> gather-only CSR reduction, no f32 atomics.
// R4: bucketed CSR build (was: 50us scatter w/ 16x write amplification);
//     float4-vectorized gather in agg with shfl_xor cross-lane reduce.
// NOTE: packing assumes N <= 65535 (here N=50000).

#define IN_DIM 64
#define HID_DIM 64
#define LAT_DIM 32
#define BCAP 5120   // bucket capacity: mean 4096, sigma ~64 -> +16 sigma

// ---------------- bucketed CSR construction ----------------

// Each block: 4096 edges (16 x 256 coalesced), LDS rank per bucket,
// one global atomicAdd per (block,bucket), then clustered pair writes.
__global__ __launch_bounds__(256) void bin_kernel(const int* __restrict__ src,
                                                  const int* __restrict__ dst,
                                                  int* __restrict__ bucket_cnt,
                                                  unsigned* __restrict__ pairs, int E) {
    __shared__ int bcnt[256];
    __shared__ int bbase[256];
    int tid = threadIdx.x;
    bcnt[tid] = 0;
    __syncthreads();
    int base = blockIdx.x * 4096;
    unsigned pk[16]; int bk[16]; int rk[16];
    #pragma unroll
    for (int i = 0; i < 16; ++i) {
        int e = base + i * 256 + tid;
        bk[i] = -1;
        if (e < E) {
            int s = __builtin_nontemporal_load(src + e);
            int d = __builtin_nontemporal_load(dst + e);
            bk[i] = d >> 8;
            pk[i] = (unsigned)s | ((unsigned)(d & 255) << 16);
            rk[i] = atomicAdd(&bcnt[bk[i]], 1);
        }
    }
    __syncthreads();
    int c = bcnt[tid];
    if (c > 0) bbase[tid] = atomicAdd(&bucket_cnt[tid], c);
    __syncthreads();
    #pragma unroll
    for (int i = 0; i < 16; ++i) {
        if (bk[i] >= 0) {
            int pos = bbase[bk[i]] + rk[i];
            if (pos < BCAP) pairs[(size_t)bk[i] * BCAP + pos] = pk[i];
        }
    }
}

// Per-bucket node-level histogram in LDS -> coalesced cnt writes.
__global__ __launch_bounds__(256) void bhist_kernel(const unsigned* __restrict__ pairs,
                                                    const int* __restrict__ bucket_cnt,
                                                    int* __restrict__ cnt, int N) {
    __shared__ int h[256];
    int b = blockIdx.x, tid = threadIdx.x;
    h[tid] = 0;
    __syncthreads();
    int c = min(bucket_cnt[b], BCAP);
    const unsigned* pb = pairs + (size_t)b * BCAP;
    for (int i = tid; i < c; i += 256)
        atomicAdd(&h[pb[i] >> 16], 1);
    __syncthreads();
    int node = b * 256 + tid;
    if (node < N) cnt[node] = h[tid];
}

// ---- scan kernel A: per-block (1024 elems, 256 thr x int4) inclusive scan ----
__global__ __launch_bounds__(256) void scan_a(const int* __restrict__ cnt,
                                              int* __restrict__ incl,
                                              int* __restrict__ bsum, int N) {
    __shared__ int wsum[4];
    int tid = threadIdx.x;
    int i0 = blockIdx.x * 1024 + tid * 4;
    int4 v = make_int4(0, 0, 0, 0);
    if (i0 + 3 < N) v = *(const int4*)(cnt + i0);
    else {
        if (i0 + 0 < N) v.x = cnt[i0 + 0];
        if (i0 + 1 < N) v.y = cnt[i0 + 1];
        if (i0 + 2 < N) v.z = cnt[i0 + 2];
        if (i0 + 3 < N) v.w = cnt[i0 + 3];
    }
    int s1 = v.x + v.y, s2 = s1 + v.z, s3 = s2 + v.w;
    int lane = tid & 63, wid = tid >> 6;
    int sc = s3;
    #pragma unroll
    for (int d = 1; d < 64; d <<= 1) {
        int t = __shfl_up(sc, d, 64);
        if (lane >= d) sc += t;
    }
    if (lane == 63) wsum[wid] = sc;
    __syncthreads();
    int woff = 0;
    #pragma unroll
    for (int w = 0; w < 4; ++w) if (w < wid) woff += wsum[w];
    int excl = woff + sc - s3;
    int o0 = excl + v.x, o1 = excl + s1, o2 = excl + s2, o3 = excl + s3;
    if (i0 + 3 < N) *(int4*)(incl + i0) = make_int4(o0, o1, o2, o3);
    else {
        if (i0 + 0 < N) incl[i0 + 0] = o0;
        if (i0 + 1 < N) incl[i0 + 1] = o1;
        if (i0 + 2 < N) incl[i0 + 2] = o2;
        if (i0 + 3 < N) incl[i0 + 3] = o3;
    }
    if (tid == 255) bsum[blockIdx.x] = woff + sc;
}

__global__ void scan_b(int* __restrict__ bsum, int NB) {
    int lane = threadIdx.x;
    int v = (lane < NB) ? bsum[lane] : 0;
    int sc = v;
    #pragma unroll
    for (int d = 1; d < 64; d <<= 1) {
        int t = __shfl_up(sc, d, 64);
        if (lane >= d) sc += t;
    }
    if (lane < NB) bsum[lane] = sc - v;
}

__global__ __launch_bounds__(256) void scan_c(const int* __restrict__ cnt,
                                              const int* __restrict__ incl,
                                              const int* __restrict__ bsum,
                                              int* __restrict__ off,
                                              float* __restrict__ dinv, int N) {
    int i = blockIdx.x * blockDim.x + threadIdx.x;
    if (i == 0) off[0] = 0;
    if (i < N) {
        int t = incl[i] + bsum[i >> 10];
        int c = cnt[i];
        off[i + 1] = t;
        dinv[i]    = rsqrtf((float)(c + 1));
    }
}

// Per-bucket scatter: cur staged in LDS, col writes land in ~16KB L2 window.
__global__ __launch_bounds__(256) void bscatter_kernel(const unsigned* __restrict__ pairs,
                                                       const int* __restrict__ bucket_cnt,
                                                       const int* __restrict__ off,
                                                       int* __restrict__ col, int N) {
    __shared__ int scur[256];
    int b = blockIdx.x, tid = threadIdx.x;
    int node = b * 256 + tid;
    scur[tid] = (node < N) ? off[node] : 0;
    __syncthreads();
    int c = min(bucket_cnt[b], BCAP);
    const unsigned* pb = pairs + (size_t)b * BCAP;
    for (int i = tid; i < c; i += 256) {
        unsigned v = pb[i];
        int p = atomicAdd(&scur[v >> 16], 1);
        col[p] = (int)(v & 0xFFFFu);
    }
}

// ---------------- GEMM (N x 64) @ (64 x OUT), scaled by dinv[row] ----------------

template<int OUT, int RT>
__global__ __launch_bounds__(256) void gemm_tile_kernel(const float* __restrict__ X,
                                                        const float* __restrict__ W,
                                                        const float* __restrict__ dinv,
                                                        float* __restrict__ G, int N) {
    constexpr int CG = OUT / 4;
    static_assert(256 / CG * 4 == RT, "RT must match 4*(256/CG)");
    __shared__ float Ws[64 * OUT];
    __shared__ float XsT[64][RT + 4];
    int tid = threadIdx.x;
    int row0 = blockIdx.x * RT;

    for (int f = 4 * tid; f < 64 * OUT; f += 1024)
        *(float4*)&Ws[f] = *(const float4*)&W[f];

    for (int f = 4 * tid; f < RT * 64; f += 1024) {
        int r  = f >> 6;
        int k0 = f & 63;
        int gr = row0 + r;
        float4 v = (gr < N) ? *(const float4*)&X[(size_t)gr * 64 + k0]
                            : make_float4(0.f, 0.f, 0.f, 0.f);
        XsT[k0 + 0][r] = v.x; XsT[k0 + 1][r] = v.y;
        XsT[k0 + 2][r] = v.z; XsT[k0 + 3][r] = v.w;
    }
    __syncthreads();

    int cr = tid % CG;
    int rr = tid / CG;
    float acc[4][4] = {};
    #pragma unroll 4
    for (int k = 0; k < 64; ++k) {
        float4 a = *(float4*)&XsT[k][4 * rr];
        float4 b = *(float4*)&Ws[k * OUT + 4 * cr];
        float av[4] = {a.x, a.y, a.z, a.w};
        float bv[4] = {b.x, b.y, b.z, b.w};
        #pragma unroll
        for (int j = 0; j < 4; ++j)
            #pragma unroll
            for (int i = 0; i < 4; ++i)
                acc[j][i] += av[j] * bv[i];
    }

    #pragma unroll
    for (int j = 0; j < 4; ++j) {
        int gr = row0 + 4 * rr + j;
        if (gr < N) {
            float s = dinv[gr];
            float4 o = make_float4(acc[j][0] * s, acc[j][1] * s,
                                   acc[j][2] * s, acc[j][3] * s);
            *(float4*)&G[(size_t)gr * OUT + 4 * cr] = o;
        }
    }
}

// ---------------- CSR aggregation (float4 gather) ----------------
// One wave per node. Row = D/4 float4s; EPI = 64/(D/4) edges per iteration.
// Lane layout: grp = lane/(D/4) picks edge within stripe, c4 = lane%(D/4) picks
// the float4 column. Virtual edge 0 = self loop. Cross-lane reduce over grp via
// shfl_xor, then lanes with grp==0 store the row.

template<int D, bool TANH>
__global__ __launch_bounds__(256) void agg_kernel(const float* __restrict__ G,
                           const int* __restrict__ off,
                           const int* __restrict__ col, const float* __restrict__ dinv,
                           const float* __restrict__ b, float* __restrict__ H, int N) {
    constexpr int Q = D / 4;          // float4s per row (16 or 8)
    constexpr int EPI = 64 / Q;       // edges per iter (4 or 8)
    int tid  = threadIdx.x;
    int lane = tid & 63;
    int w    = tid >> 6;
    int node = blockIdx.x * 4 + w;
    if (node >= N) return;
    int grp = lane / Q;
    int c4  = lane % Q;
    int p0  = off[node];
    int total = off[node + 1] - p0 + 1;   // + self loop
    float4 acc = make_float4(0.f, 0.f, 0.f, 0.f);
    #pragma unroll 2
    for (int base = 0; base < total; base += EPI) {
        int e = base + grp;
        if (e < total) {
            int s = (e == 0) ? node : col[p0 + e - 1];
            float4 v = *(const float4*)&G[(size_t)s * D + 4 * c4];
            acc.x += v.x; acc.y += v.y; acc.z += v.z; acc.w += v.w;
        }
    }
    #pragma unroll
    for (int m = Q; m < 64; m <<= 1) {
        acc.x += __shfl_xor(acc.x, m, 64);
        acc.y += __shfl_xor(acc.y, m, 64);
        acc.z += __shfl_xor(acc.z, m, 64);
        acc.w += __shfl_xor(acc.w, m, 64);
    }
    if (grp == 0) {
        float s = dinv[node];
        float4 bq = *(const float4*)&b[4 * c4];
        float4 o;
        o.x = s * acc.x + bq.x; o.y = s * acc.y + bq.y;
        o.z = s * acc.z + bq.z; o.w = s * acc.w + bq.w;
        if (TANH) { o.x = tanhf(o.x); o.y = tanhf(o.y); o.z = tanhf(o.z); o.w = tanhf(o.w); }
        *(float4*)&H[(size_t)node * D + 4 * c4] = o;
    }
}

// ---------------- launch ----------------

static inline size_t align256(size_t x) { return (x + 255) & ~(size_t)255; }

extern "C" void kernel_launch(void* const* d_in, const int* in_sizes, int n_in,
                              void* d_out, int out_size, void* d_ws, size_t ws_size,
                              hipStream_t stream) {
    const float* x   = (const float*)d_in[0];
    const int*   ei  = (const int*)d_in[1];
    const float* W1  = (const float*)d_in[2];
    const float* b1  = (const float*)d_in[3];
    const float* W2  = (const float*)d_in[4];
    const float* b2  = (const float*)d_in[5];
    const float* W3  = (const float*)d_in[6];
    const float* b3  = (const float*)d_in[7];
    float* out = (float*)d_out;

    const int N = in_sizes[0] / IN_DIM;   // 50000
    const int E = in_sizes[1] / 2;        // 800000
    const int* src = ei;
    const int* dst = ei + E;
    const int NB   = (N + 1023) / 1024;   // scan blocks (49)
    const int NBK  = (N + 255) / 256;     // buckets (196)
    const int BINB = (E + 4095) / 4096;   // bin blocks (196)

    // workspace layout
    char* ws = (char*)d_ws;
    size_t o = 0;
    int*      cnt   = (int*)(ws + o);      o = align256(o + (size_t)N * 4);
    int*      off   = (int*)(ws + o);      o = align256(o + (size_t)(N + 1) * 4);
    float*    dinv  = (float*)(ws + o);    o = align256(o + (size_t)N * 4);
    int*      incl  = (int*)(ws + o);      o = align256(o + (size_t)N * 4);
    int*      bsum  = (int*)(ws + o);      o = align256(o + (size_t)NB * 4);
    int*      bkcnt = (int*)(ws + o);      o = align256(o + 256 * 4);
    unsigned* pairs = (unsigned*)(ws + o); o = align256(o + (size_t)NBK * BCAP * 4);
    int*      col   = (int*)(ws + o);      o = align256(o + (size_t)E * 4);
    float*    bufG  = (float*)(ws + o);    o = align256(o + (size_t)N * HID_DIM * 4);
    float*    bufH  = (float*)(ws + o);    o = align256(o + (size_t)N * HID_DIM * 4);
    (void)ws_size;

    // CSR build
    hipMemsetAsync(bkcnt, 0, 256 * 4, stream);
    bin_kernel<<<BINB, 256, 0, stream>>>(src, dst, bkcnt, pairs, E);
    bhist_kernel<<<NBK, 256, 0, stream>>>(pairs, bkcnt, cnt, N);
    scan_a<<<NB, 256, 0, stream>>>(cnt, incl, bsum, N);
    scan_b<<<1, 64, 0, stream>>>(bsum, NB);
    scan_c<<<(N + 255) / 256, 256, 0, stream>>>(cnt, incl, bsum, off, dinv, N);
    bscatter_kernel<<<NBK, 256, 0, stream>>>(pairs, bkcnt, off, col, N);

    const int g64_grid = (N + 63) / 64;    // RT=64
    const int g32_grid = (N + 127) / 128;  // RT=128
    const int agg_grid = (N + 3) / 4;      // 1 node/wave, 4 waves/block

    // layer 1
    gemm_tile_kernel<HID_DIM, 64><<<g64_grid, 256, 0, stream>>>(x, W1, dinv, bufG, N);
    agg_kernel<HID_DIM, true><<<agg_grid, 256, 0, stream>>>(bufG, off, col, dinv, b1, bufH, N);

    // layer 2
    gemm_tile_kernel<HID_DIM, 64><<<g64_grid, 256, 0, stream>>>(bufH, W2, dinv, bufG, N);
    agg_kernel<HID_DIM, true><<<agg_grid, 256, 0, stream>>>(bufG, off, col, dinv, b2, bufH, N);

    // layer 3 (no tanh, D=32) -> d_out
    gemm_tile_kernel<LAT_DIM, 128><<<g32_grid, 256, 0, stream>>>(bufH, W3, dinv, bufG, N);
    agg_kernel<LAT_DIM, false><<<agg_grid, 256, 0, stream>>>(bufG, off, col, dinv, b3, out, N);
}

// Round 6
// 238.575 us; speedup vs baseline: 2.4575x; 1.0562x over previous
//
#include <hip/hip_runtime.h>
#include <hip/hip_bf16.h>

// 3-layer GCN encoder on MI355X.
//   CSR build (bucketed, no random global writes, no global scan arrays):
//     bin:    edges -> 196 buckets of 256 nodes (dst>>8), packed src|localdst<<16
//     bscan:  1-block exclusive scan of bucket counts -> boff
//     boff_k: per-bucket LDS histogram + block scan -> off, dinv (fused)
//     bscat:  per-bucket scatter, off staged in LDS, col writes L2-local
//   Per layer: g = (h @ W) * dinv ; h = act(dinv * (sum_{s in N(d)} g[s] + g[d]) + b)
// norm factored into two dinv scalings -> gather-only CSR reduction, no f32 atomics.
// R5 (resubmit; prior bench failed on GPU acquisition):
//     gemm staging row-major (was 8-way LDS conflict on transpose store);
//     scan pipeline folded into bucket kernels (13 -> 11 dispatches);
//     agg remapped to 8 lanes/row x 8 edges in flight (2-4x outstanding gathers).
// NOTE: packing assumes N <= 65535 (here N=50000).

#define IN_DIM 64
#define HID_DIM 64
#define LAT_DIM 32
#define BCAP 5120   // bucket capacity: mean 4081, sigma ~64 -> +16 sigma

// ---------------- bucketed CSR construction ----------------

__global__ __launch_bounds__(256) void bin_kernel(const int* __restrict__ src,
                                                  const int* __restrict__ dst,
                                                  int* __restrict__ bucket_cnt,
                                                  unsigned* __restrict__ pairs, int E) {
    __shared__ int bcnt[256];
    __shared__ int bbase[256];
    int tid = threadIdx.x;
    bcnt[tid] = 0;
    __syncthreads();
    int base = blockIdx.x * 4096;
    unsigned pk[16]; int bk[16]; int rk[16];
    #pragma unroll
    for (int i = 0; i < 16; ++i) {
        int e = base + i * 256 + tid;
        bk[i] = -1;
        if (e < E) {
            int s = __builtin_nontemporal_load(src + e);
            int d = __builtin_nontemporal_load(dst + e);
            bk[i] = d >> 8;
            pk[i] = (unsigned)s | ((unsigned)(d & 255) << 16);
            rk[i] = atomicAdd(&bcnt[bk[i]], 1);
        }
    }
    __syncthreads();
    int c = bcnt[tid];
    if (c > 0) bbase[tid] = atomicAdd(&bucket_cnt[tid], c);
    __syncthreads();
    #pragma unroll
    for (int i = 0; i < 16; ++i) {
        if (bk[i] >= 0) {
            int pos = bbase[bk[i]] + rk[i];
            if (pos < BCAP) pairs[(size_t)bk[i] * BCAP + pos] = pk[i];
        }
    }
}

// 1-block exclusive scan of bucket counts (NBK=196 <= 256).
__global__ __launch_bounds__(256) void bscan_kernel(const int* __restrict__ bucket_cnt,
                                                    int* __restrict__ boff, int NBK) {
    __shared__ int wtot[4];
    int tid = threadIdx.x;
    int lane = tid & 63, wid = tid >> 6;
    int v = (tid < NBK) ? min(bucket_cnt[tid], BCAP) : 0;
    int sc = v;
    #pragma unroll
    for (int d = 1; d < 64; d <<= 1) {
        int t = __shfl_up(sc, d, 64);
        if (lane >= d) sc += t;
    }
    if (lane == 63) wtot[wid] = sc;
    __syncthreads();
    int woff = 0;
    #pragma unroll
    for (int w = 0; w < 4; ++w) if (w < wid) woff += wtot[w];
    boff[tid] = woff + sc - v;   // exclusive
}

// Per-bucket histogram + block scan -> off[node+1], dinv[node]. Fuses the old
// bhist + global scan chain (bucket totals == bucket_cnt, so no global pass).
__global__ __launch_bounds__(256) void build_off_kernel(const unsigned* __restrict__ pairs,
                                                        const int* __restrict__ bucket_cnt,
                                                        const int* __restrict__ boff,
                                                        int* __restrict__ off,
                                                        float* __restrict__ dinv, int N) {
    __shared__ int h[256];
    __shared__ int wtot[4];
    int b = blockIdx.x, tid = threadIdx.x;
    h[tid] = 0;
    __syncthreads();
    int c = min(bucket_cnt[b], BCAP);
    const unsigned* pb = pairs + (size_t)b * BCAP;
    for (int i = tid; i < c; i += 256)
        atomicAdd(&h[pb[i] >> 16], 1);
    __syncthreads();
    int v = h[tid];
    int lane = tid & 63, wid = tid >> 6;
    int sc = v;
    #pragma unroll
    for (int d = 1; d < 64; d <<= 1) {
        int t = __shfl_up(sc, d, 64);
        if (lane >= d) sc += t;
    }
    if (lane == 63) wtot[wid] = sc;
    __syncthreads();
    int woff = 0;
    #pragma unroll
    for (int w = 0; w < 4; ++w) if (w < wid) woff += wtot[w];
    int incl = woff + sc;
    int node = b * 256 + tid;
    if (node < N) {
        off[node + 1] = boff[b] + incl;
        dinv[node]    = rsqrtf((float)(v + 1));
    }
    if (b == 0 && tid == 0) off[0] = 0;
}

// Per-bucket scatter: cur staged in LDS, col writes land in ~16KB L2 window.
__global__ __launch_bounds__(256) void bscatter_kernel(const unsigned* __restrict__ pairs,
                                                       const int* __restrict__ bucket_cnt,
                                                       const int* __restrict__ off,
                                                       int* __restrict__ col, int N) {
    __shared__ int scur[256];
    int b = blockIdx.x, tid = threadIdx.x;
    int node = b * 256 + tid;
    scur[tid] = (node < N) ? off[node] : 0;
    __syncthreads();
    int c = min(bucket_cnt[b], BCAP);
    const unsigned* pb = pairs + (size_t)b * BCAP;
    for (int i = tid; i < c; i += 256) {
        unsigned v = pb[i];
        int p = atomicAdd(&scur[v >> 16], 1);
        col[p] = (int)(v & 0xFFFFu);
    }
}

// ---------------- GEMM (N x 64) @ (64 x OUT), scaled by dinv[row] ----------------
// Row-major X staging (coalesced float4 stores, no transpose). Compute reads:
// 4 scalar a-broadcasts (free) + one 2-way b128 for W. 4x4 outputs/thread.

template<int OUT, int RT>
__global__ __launch_bounds__(256) void gemm_tile_kernel(const float* __restrict__ X,
                                                        const float* __restrict__ W,
                                                        const float* __restrict__ dinv,
                                                        float* __restrict__ G, int N) {
    constexpr int CG = OUT / 4;
    static_assert(256 / CG * 4 == RT, "RT must match 4*(256/CG)");
    __shared__ float Ws[64 * OUT];
    __shared__ float Xs[RT][64 + 4];
    int tid = threadIdx.x;
    int row0 = blockIdx.x * RT;

    for (int f = 4 * tid; f < 64 * OUT; f += 1024)
        *(float4*)&Ws[f] = *(const float4*)&W[f];

    for (int f = 4 * tid; f < RT * 64; f += 1024) {
        int r  = f >> 6;
        int k0 = f & 63;
        int gr = row0 + r;
        float4 v = (gr < N) ? *(const float4*)&X[(size_t)gr * 64 + k0]
                            : make_float4(0.f, 0.f, 0.f, 0.f);
        *(float4*)&Xs[r][k0] = v;
    }
    __syncthreads();

    int cr = tid % CG;
    int rr = tid / CG;
    float acc[4][4] = {};
    #pragma unroll 4
    for (int k = 0; k < 64; ++k) {
        float4 bv = *(float4*)&Ws[k * OUT + 4 * cr];
        float av[4] = {Xs[4 * rr + 0][k], Xs[4 * rr + 1][k],
                       Xs[4 * rr + 2][k], Xs[4 * rr + 3][k]};
        float bb[4] = {bv.x, bv.y, bv.z, bv.w};
        #pragma unroll
        for (int j = 0; j < 4; ++j)
            #pragma unroll
            for (int i = 0; i < 4; ++i)
                acc[j][i] += av[j] * bb[i];
    }

    #pragma unroll
    for (int j = 0; j < 4; ++j) {
        int gr = row0 + 4 * rr + j;
        if (gr < N) {
            float s = dinv[gr];
            float4 o = make_float4(acc[j][0] * s, acc[j][1] * s,
                                   acc[j][2] * s, acc[j][3] * s);
            *(float4*)&G[(size_t)gr * OUT + 4 * cr] = o;
        }
    }
}

// ---------------- CSR aggregation (float4 gather, 8 lanes/row) ----------------
// One wave per node. 8 edges in flight/iter; lane = (grp: edge slot, c4: column).
// D=64: each lane owns float4 cols c4 and c4+8 (2 outstanding loads per slot).
// Virtual slot 0 = self loop. 3-round shfl_xor reduce over grp, grp==0 stores.

template<int D, bool TANH>
__global__ __launch_bounds__(256) void agg_kernel(const float* __restrict__ G,
                           const int* __restrict__ off,
                           const int* __restrict__ col, const float* __restrict__ dinv,
                           const float* __restrict__ b, float* __restrict__ H, int N) {
    constexpr int F = D / 32;         // float4s per lane (2 for D=64, 1 for D=32)
    int tid  = threadIdx.x;
    int lane = tid & 63;
    int w    = tid >> 6;
    int node = blockIdx.x * 4 + w;
    if (node >= N) return;
    int grp = lane >> 3;
    int c4  = lane & 7;
    int p0  = off[node];
    int total = off[node + 1] - p0 + 1;   // + self loop
    float4 a0 = make_float4(0.f, 0.f, 0.f, 0.f);
    float4 a1 = make_float4(0.f, 0.f, 0.f, 0.f);
    #pragma unroll 2
    for (int base = 0; base < total; base += 8) {
        int e = base + grp;
        if (e < total) {
            int s = (e == 0) ? node : col[p0 + e - 1];
            const float4* row = (const float4*)&G[(size_t)s * D];
            float4 u = row[c4];
            a0.x += u.x; a0.y += u.y; a0.z += u.z; a0.w += u.w;
            if (F == 2) {
                float4 u2 = row[c4 + 8];
                a1.x += u2.x; a1.y += u2.y; a1.z += u2.z; a1.w += u2.w;
            }
        }
    }
    #pragma unroll
    for (int m = 8; m < 64; m <<= 1) {
        a0.x += __shfl_xor(a0.x, m, 64);
        a0.y += __shfl_xor(a0.y, m, 64);
        a0.z += __shfl_xor(a0.z, m, 64);
        a0.w += __shfl_xor(a0.w, m, 64);
        if (F == 2) {
            a1.x += __shfl_xor(a1.x, m, 64);
            a1.y += __shfl_xor(a1.y, m, 64);
            a1.z += __shfl_xor(a1.z, m, 64);
            a1.w += __shfl_xor(a1.w, m, 64);
        }
    }
    if (grp == 0) {
        float s = dinv[node];
        float4 bq = *(const float4*)&b[4 * c4];
        float4 o;
        o.x = s * a0.x + bq.x; o.y = s * a0.y + bq.y;
        o.z = s * a0.z + bq.z; o.w = s * a0.w + bq.w;
        if (TANH) { o.x = tanhf(o.x); o.y = tanhf(o.y); o.z = tanhf(o.z); o.w = tanhf(o.w); }
        *(float4*)&H[(size_t)node * D + 4 * c4] = o;
        if (F == 2) {
            float4 bq1 = *(const float4*)&b[4 * (c4 + 8)];
            float4 o1;
            o1.x = s * a1.x + bq1.x; o1.y = s * a1.y + bq1.y;
            o1.z = s * a1.z + bq1.z; o1.w = s * a1.w + bq1.w;
            if (TANH) { o1.x = tanhf(o1.x); o1.y = tanhf(o1.y);
                        o1.z = tanhf(o1.z); o1.w = tanhf(o1.w); }
            *(float4*)&H[(size_t)node * D + 4 * (c4 + 8)] = o1;
        }
    }
}

// ---------------- launch ----------------

static inline size_t align256(size_t x) { return (x + 255) & ~(size_t)255; }

extern "C" void kernel_launch(void* const* d_in, const int* in_sizes, int n_in,
                              void* d_out, int out_size, void* d_ws, size_t ws_size,
                              hipStream_t stream) {
    const float* x   = (const float*)d_in[0];
    const int*   ei  = (const int*)d_in[1];
    const float* W1  = (const float*)d_in[2];
    const float* b1  = (const float*)d_in[3];
    const float* W2  = (const float*)d_in[4];
    const float* b2  = (const float*)d_in[5];
    const float* W3  = (const float*)d_in[6];
    const float* b3  = (const float*)d_in[7];
    float* out = (float*)d_out;

    const int N = in_sizes[0] / IN_DIM;   // 50000
    const int E = in_sizes[1] / 2;        // 800000
    const int* src = ei;
    const int* dst = ei + E;
    const int NBK  = (N + 255) / 256;     // buckets (196)
    const int BINB = (E + 4095) / 4096;   // bin blocks (196)

    // workspace layout
    char* ws = (char*)d_ws;
    size_t o = 0;
    int*      bkcnt = (int*)(ws + o);      o = align256(o + 256 * 4);
    int*      boff  = (int*)(ws + o);      o = align256(o + 256 * 4);
    int*      off   = (int*)(ws + o);      o = align256(o + (size_t)(N + 1) * 4);
    float*    dinv  = (float*)(ws + o);    o = align256(o + (size_t)N * 4);
    unsigned* pairs = (unsigned*)(ws + o); o = align256(o + (size_t)NBK * BCAP * 4);
    int*      col   = (int*)(ws + o);      o = align256(o + (size_t)E * 4);
    float*    bufG  = (float*)(ws + o);    o = align256(o + (size_t)N * HID_DIM * 4);
    float*    bufH  = (float*)(ws + o);    o = align256(o + (size_t)N * HID_DIM * 4);
    (void)ws_size;

    // CSR build
    hipMemsetAsync(bkcnt, 0, 256 * 4, stream);
    bin_kernel<<<BINB, 256, 0, stream>>>(src, dst, bkcnt, pairs, E);
    bscan_kernel<<<1, 256, 0, stream>>>(bkcnt, boff, NBK);
    build_off_kernel<<<NBK, 256, 0, stream>>>(pairs, bkcnt, boff, off, dinv, N);

    const int g64_grid = (N + 63) / 64;    // RT=64
    const int g32_grid = (N + 127) / 128;  // RT=128
    const int agg_grid = (N + 3) / 4;      // 1 node/wave, 4 waves/block

    // gemm1 depends only on dinv -> launch before bscatter to keep CUs busy
    gemm_tile_kernel<HID_DIM, 64><<<g64_grid, 256, 0, stream>>>(x, W1, dinv, bufG, N);
    bscatter_kernel<<<NBK, 256, 0, stream>>>(pairs, bkcnt, off, col, N);

    // layer 1
    agg_kernel<HID_DIM, true><<<agg_grid, 256, 0, stream>>>(bufG, off, col, dinv, b1, bufH, N);
    // layer 2
    gemm_tile_kernel<HID_DIM, 64><<<g64_grid, 256, 0, stream>>>(bufH, W2, dinv, bufG, N);
    agg_kernel<HID_DIM, true><<<agg_grid, 256, 0, stream>>>(bufG, off, col, dinv, b2, bufH, N);
    // layer 3 (no tanh, D=32) -> d_out
    gemm_tile_kernel<LAT_DIM, 128><<<g32_grid, 256, 0, stream>>>(bufH, W3, dinv, bufG, N);
    agg_kernel<LAT_DIM, false><<<agg_grid, 256, 0, stream>>>(bufG, off, col, dinv, b3, out, N);
}

// Round 7
// 236.282 us; speedup vs baseline: 2.4813x; 1.0097x over previous
//
#include <hip/hip_runtime.h>
#include <hip/hip_fp16.h>
#include <type_traits>

// 3-layer GCN encoder on MI355X.
//   CSR build: bin (bucket by dst>>8, packed src|localdst<<16) ->
//              build_csr (fused: redundant bucket-scan + LDS histogram +
//                         block scan -> off/dinv, then in-LDS scatter -> col)
//   Per layer: g = (h @ W) * dinv  [fp16 out] ;
//              h = act(dinv * (sum_{s in N(d)+self} g[s]) + b)
// norm factored into two dinv scalings -> gather-only CSR reduction, no f32 atomics.
// R7: fp16 internal G/H buffers (halves gather traffic, 6.4MB table ~L2-resident);
//     CSR build fused 4->2 kernels (11 -> 9 dispatches). All accumulation f32.
// NOTE: packing assumes N <= 65535 (here N=50000).

#define IN_DIM 64
#define HID_DIM 64
#define LAT_DIM 32
#define BCAP 5120   // bucket capacity: mean 4081, sigma ~64 -> +16 sigma

typedef __attribute__((ext_vector_type(8))) _Float16 half8;
typedef __attribute__((ext_vector_type(4))) _Float16 half4;

// ---------------- bucketed CSR construction ----------------

__global__ __launch_bounds__(256) void bin_kernel(const int* __restrict__ src,
                                                  const int* __restrict__ dst,
                                                  int* __restrict__ bucket_cnt,
                                                  unsigned* __restrict__ pairs, int E) {
    __shared__ int bcnt[256];
    __shared__ int bbase[256];
    int tid = threadIdx.x;
    bcnt[tid] = 0;
    __syncthreads();
    int base = blockIdx.x * 4096;
    unsigned pk[16]; int bk[16]; int rk[16];
    #pragma unroll
    for (int i = 0; i < 16; ++i) {
        int e = base + i * 256 + tid;
        bk[i] = -1;
        if (e < E) {
            int s = __builtin_nontemporal_load(src + e);
            int d = __builtin_nontemporal_load(dst + e);
            bk[i] = d >> 8;
            pk[i] = (unsigned)s | ((unsigned)(d & 255) << 16);
            rk[i] = atomicAdd(&bcnt[bk[i]], 1);
        }
    }
    __syncthreads();
    int c = bcnt[tid];
    if (c > 0) bbase[tid] = atomicAdd(&bucket_cnt[tid], c);
    __syncthreads();
    #pragma unroll
    for (int i = 0; i < 16; ++i) {
        if (bk[i] >= 0) {
            int pos = bbase[bk[i]] + rk[i];
            if (pos < BCAP) pairs[(size_t)bk[i] * BCAP + pos] = pk[i];
        }
    }
}

// Fused: (A) every block scans all bucket counts in LDS (cheap, redundant),
// (B) per-bucket node histogram, (C) block scan -> off/dinv, (D) in-LDS scatter.
__global__ __launch_bounds__(256) void build_csr_kernel(const unsigned* __restrict__ pairs,
                                                        const int* __restrict__ bucket_cnt,
                                                        int* __restrict__ off,
                                                        float* __restrict__ dinv,
                                                        int* __restrict__ col,
                                                        int N, int NBK) {
    __shared__ int sboff[256];
    __shared__ int h[256];
    __shared__ int scur[256];
    __shared__ int wtot[4];
    int b = blockIdx.x, tid = threadIdx.x;
    int lane = tid & 63, wid = tid >> 6;

    // A: exclusive scan of bucket counts (all NBK<=256 in one block pass)
    int v = (tid < NBK) ? min(bucket_cnt[tid], BCAP) : 0;
    int sc = v;
    #pragma unroll
    for (int d = 1; d < 64; d <<= 1) {
        int t = __shfl_up(sc, d, 64);
        if (lane >= d) sc += t;
    }
    if (lane == 63) wtot[wid] = sc;
    h[tid] = 0;
    __syncthreads();
    int woff = 0;
    #pragma unroll
    for (int w = 0; w < 4; ++w) if (w < wid) woff += wtot[w];
    sboff[tid] = woff + sc - v;
    __syncthreads();
    int boff_b = sboff[b];

    // B: histogram of this bucket's local dst
    int c = min(bucket_cnt[b], BCAP);
    const unsigned* pb = pairs + (size_t)b * BCAP;
    for (int i = tid; i < c; i += 256)
        atomicAdd(&h[pb[i] >> 16], 1);
    __syncthreads();

    // C: block scan of histogram -> off / dinv / scur
    int hv = h[tid];
    int sc2 = hv;
    #pragma unroll
    for (int d = 1; d < 64; d <<= 1) {
        int t = __shfl_up(sc2, d, 64);
        if (lane >= d) sc2 += t;
    }
    if (lane == 63) wtot[wid] = sc2;
    __syncthreads();
    int woff2 = 0;
    #pragma unroll
    for (int w = 0; w < 4; ++w) if (w < wid) woff2 += wtot[w];
    int incl = woff2 + sc2;
    int node = b * 256 + tid;
    scur[tid] = boff_b + incl - hv;            // exclusive start for this node
    if (node < N) {
        off[node + 1] = boff_b + incl;
        dinv[node]    = rsqrtf((float)(hv + 1));
    }
    if (b == 0 && tid == 0) off[0] = 0;
    __syncthreads();

    // D: scatter (col writes land in this bucket's contiguous window)
    for (int i = tid; i < c; i += 256) {
        unsigned p = pb[i];
        int pos = atomicAdd(&scur[p >> 16], 1);
        col[pos] = (int)(p & 0xFFFFu);
    }
}

// ---------------- GEMM (N x 64) @ (64 x OUT) * dinv[row] -> fp16 G ----------------
// Row-major X staging (coalesced, 272B row stride = 16B-aligned). 4x4 outputs/thread;
// a-reads are 16-lane broadcasts (free), b-read one 2-way b128 (free).

template<int OUT, int RT, typename TIN>
__global__ __launch_bounds__(256) void gemm_tile_kernel(const TIN* __restrict__ X,
                                                        const float* __restrict__ W,
                                                        const float* __restrict__ dinv,
                                                        _Float16* __restrict__ G, int N) {
    constexpr int CG = OUT / 4;
    static_assert(256 / CG * 4 == RT, "RT must match 4*(256/CG)");
    __shared__ float Ws[64 * OUT];
    __shared__ float Xs[RT][64 + 4];
    int tid = threadIdx.x;
    int row0 = blockIdx.x * RT;

    for (int f = 4 * tid; f < 64 * OUT; f += 1024)
        *(float4*)&Ws[f] = *(const float4*)&W[f];

    if constexpr (std::is_same<TIN, float>::value) {
        for (int f = 4 * tid; f < RT * 64; f += 1024) {
            int r = f >> 6, k0 = f & 63, gr = row0 + r;
            float4 v = (gr < N) ? *(const float4*)&X[(size_t)gr * 64 + k0]
                                : make_float4(0.f, 0.f, 0.f, 0.f);
            *(float4*)&Xs[r][k0] = v;
        }
    } else {
        for (int f = 8 * tid; f < RT * 64; f += 2048) {
            int r = f >> 6, k0 = f & 63, gr = row0 + r;
            if (gr < N) {
                half8 v = *(const half8*)&X[(size_t)gr * 64 + k0];
                #pragma unroll
                for (int i = 0; i < 8; ++i) Xs[r][k0 + i] = (float)v[i];
            } else {
                #pragma unroll
                for (int i = 0; i < 8; ++i) Xs[r][k0 + i] = 0.f;
            }
        }
    }
    __syncthreads();

    int cr = tid % CG;
    int rr = tid / CG;
    float acc[4][4] = {};
    #pragma unroll 4
    for (int k = 0; k < 64; ++k) {
        float4 bv = *(float4*)&Ws[k * OUT + 4 * cr];
        float av[4] = {Xs[4 * rr + 0][k], Xs[4 * rr + 1][k],
                       Xs[4 * rr + 2][k], Xs[4 * rr + 3][k]};
        float bb[4] = {bv.x, bv.y, bv.z, bv.w};
        #pragma unroll
        for (int j = 0; j < 4; ++j)
            #pragma unroll
            for (int i = 0; i < 4; ++i)
                acc[j][i] += av[j] * bb[i];
    }

    #pragma unroll
    for (int j = 0; j < 4; ++j) {
        int gr = row0 + 4 * rr + j;
        if (gr < N) {
            float s = dinv[gr];
            half4 o;
            #pragma unroll
            for (int i = 0; i < 4; ++i) o[i] = (_Float16)(acc[j][i] * s);
            *(half4*)&G[(size_t)gr * OUT + 4 * cr] = o;
        }
    }
}

// ---------------- CSR aggregation (fp16 gather, f32 accumulate) ----------------
// One wave per node. Row = D halves (128B / 64B); lane = (grp: edge slot, c4: 16B
// chunk). D=64: 8 slots x 8 chunks; D=32: 16 slots x 4 chunks. Virtual slot 0 =
// self loop. shfl_xor reduce over grp; grp==0 lanes store.

template<int D, bool TANH, typename TOUT>
__global__ __launch_bounds__(256) void agg_kernel(const _Float16* __restrict__ G,
                           const int* __restrict__ off,
                           const int* __restrict__ col, const float* __restrict__ dinv,
                           const float* __restrict__ b, TOUT* __restrict__ H, int N) {
    constexpr int CHUNKS = D / 8;          // 8 (D=64) or 4 (D=32)
    constexpr int EPI = 64 / CHUNKS;       // 8 or 16 edge slots per iter
    int tid  = threadIdx.x;
    int lane = tid & 63;
    int w    = tid >> 6;
    int node = blockIdx.x * 4 + w;
    if (node >= N) return;
    int grp = lane / CHUNKS;
    int c4  = lane % CHUNKS;
    int p0  = off[node];
    int total = off[node + 1] - p0 + 1;    // + self loop
    float acc[8] = {};
    #pragma unroll 2
    for (int base = 0; base < total; base += EPI) {
        int e = base + grp;
        if (e < total) {
            int s = (e == 0) ? node : col[p0 + e - 1];
            half8 u = *(const half8*)&G[(size_t)s * D + 8 * c4];
            #pragma unroll
            for (int i = 0; i < 8; ++i) acc[i] += (float)u[i];
        }
    }
    #pragma unroll
    for (int m = CHUNKS; m < 64; m <<= 1) {
        #pragma unroll
        for (int i = 0; i < 8; ++i) acc[i] += __shfl_xor(acc[i], m, 64);
    }
    if (grp == 0) {
        float s = dinv[node];
        float o[8];
        #pragma unroll
        for (int i = 0; i < 8; ++i) {
            o[i] = s * acc[i] + b[8 * c4 + i];
            if (TANH) o[i] = tanhf(o[i]);
        }
        if constexpr (std::is_same<TOUT, _Float16>::value) {
            half8 hv;
            #pragma unroll
            for (int i = 0; i < 8; ++i) hv[i] = (_Float16)o[i];
            *(half8*)&H[(size_t)node * D + 8 * c4] = hv;
        } else {
            float4 f0 = make_float4(o[0], o[1], o[2], o[3]);
            float4 f1 = make_float4(o[4], o[5], o[6], o[7]);
            *(float4*)&H[(size_t)node * D + 8 * c4 + 0] = f0;
            *(float4*)&H[(size_t)node * D + 8 * c4 + 4] = f1;
        }
    }
}

// ---------------- launch ----------------

static inline size_t align256(size_t x) { return (x + 255) & ~(size_t)255; }

extern "C" void kernel_launch(void* const* d_in, const int* in_sizes, int n_in,
                              void* d_out, int out_size, void* d_ws, size_t ws_size,
                              hipStream_t stream) {
    const float* x   = (const float*)d_in[0];
    const int*   ei  = (const int*)d_in[1];
    const float* W1  = (const float*)d_in[2];
    const float* b1  = (const float*)d_in[3];
    const float* W2  = (const float*)d_in[4];
    const float* b2  = (const float*)d_in[5];
    const float* W3  = (const float*)d_in[6];
    const float* b3  = (const float*)d_in[7];
    float* out = (float*)d_out;

    const int N = in_sizes[0] / IN_DIM;   // 50000
    const int E = in_sizes[1] / 2;        // 800000
    const int* src = ei;
    const int* dst = ei + E;
    const int NBK  = (N + 255) / 256;     // buckets (196)
    const int BINB = (E + 4095) / 4096;   // bin blocks (196)

    // workspace layout
    char* ws = (char*)d_ws;
    size_t o = 0;
    int*       bkcnt = (int*)(ws + o);       o = align256(o + 256 * 4);
    int*       off   = (int*)(ws + o);       o = align256(o + (size_t)(N + 1) * 4);
    float*     dinv  = (float*)(ws + o);     o = align256(o + (size_t)N * 4);
    unsigned*  pairs = (unsigned*)(ws + o);  o = align256(o + (size_t)NBK * BCAP * 4);
    int*       col   = (int*)(ws + o);       o = align256(o + (size_t)E * 4);
    _Float16*  bufG  = (_Float16*)(ws + o);  o = align256(o + (size_t)N * HID_DIM * 2);
    _Float16*  bufH  = (_Float16*)(ws + o);  o = align256(o + (size_t)N * HID_DIM * 2);
    (void)ws_size;

    // CSR build (2 kernels + tiny memset)
    hipMemsetAsync(bkcnt, 0, 256 * 4, stream);
    bin_kernel<<<BINB, 256, 0, stream>>>(src, dst, bkcnt, pairs, E);
    build_csr_kernel<<<NBK, 256, 0, stream>>>(pairs, bkcnt, off, dinv, col, N, NBK);

    const int g64_grid = (N + 63) / 64;    // RT=64
    const int g32_grid = (N + 127) / 128;  // RT=128
    const int agg_grid = (N + 3) / 4;      // 1 node/wave, 4 waves/block

    // layer 1 (f32 input x)
    gemm_tile_kernel<HID_DIM, 64, float><<<g64_grid, 256, 0, stream>>>(x, W1, dinv, bufG, N);
    agg_kernel<HID_DIM, true, _Float16><<<agg_grid, 256, 0, stream>>>(bufG, off, col, dinv, b1, bufH, N);
    // layer 2 (fp16 input)
    gemm_tile_kernel<HID_DIM, 64, _Float16><<<g64_grid, 256, 0, stream>>>(bufH, W2, dinv, bufG, N);
    agg_kernel<HID_DIM, true, _Float16><<<agg_grid, 256, 0, stream>>>(bufG, off, col, dinv, b2, bufH, N);
    // layer 3 (fp16 input, f32 output, no tanh, D=32)
    gemm_tile_kernel<LAT_DIM, 128, _Float16><<<g32_grid, 256, 0, stream>>>(bufH, W3, dinv, bufG, N);
    agg_kernel<LAT_DIM, false, float><<<agg_grid, 256, 0, stream>>>(bufG, off, col, dinv, b3, out, N);
}